// Round 13
// baseline (21.009 us; speedup 1.0000x reference)
//
#include <hip/hip_runtime.h>
#include <hip/hip_fp16.h>

// bg: (1,4,32,32,32,16) f32 ; gm: (1,1,128,128,128) f32 ; out: (1,4,128,128,128) f32
//
// v12: two-tile double-buffered pipeline on the proven v11 structure.
// Block = tile pair (bi,bj,bk=2m / 2m+1), each 8x8x16 voxels, 256 threads.
// LDS: 2 x 96-node dup-slot fp16 buffers (26112 B each, 52224 B total).
// Flow: stage buf0 | barrier | issue tile1 loads (16-32 VGPR window) |
// interp tile0 | sched_barrier | pack+write buf1 (vmcnt waits here) |
// barrier | interp tile1.  Stage item = (node, 4-t seg): 4 x dwordx4 loads.

#define S_ (31.0f / 127.0f)
#define CH_STRIDE 524288
#define TOTAL 2097152

#define NX 4
#define NY 4
#define NZ 6
#define NNODES (NX * NY * NZ)      // 96
#define NODE_DW 68
#define BUF_DW (NNODES * NODE_DW)  // 6528 dw = 26112 B

#define PK(x, y) __builtin_bit_cast(float, __floats2half2_rn((x), (y)))
#define H2(f) __builtin_bit_cast(__half2, f)

typedef float vf4 __attribute__((ext_vector_type(4)));

__device__ __forceinline__ void nt_store4(float* p, float a, float b, float c, float d) {
    vf4 v; v.x = a; v.y = b; v.z = c; v.w = d;
    __builtin_nontemporal_store(v, (vf4*)p);
}

// pack 4 channel-float4s (t = 4s4..4s4+3) into dup-slot layout at buf[d0]
__device__ __forceinline__ void pack_write(float* buf, int s0, int s4,
                                           const float4& L0, const float4& L1,
                                           const float4& L2, const float4& L3) {
    float2 p0, p1, p2, p3;
    p0.x = PK(L0.x, L1.x); p0.y = PK(L2.x, L3.x);
    p1.x = PK(L0.y, L1.y); p1.y = PK(L2.y, L3.y);
    p2.x = PK(L0.z, L1.z); p2.y = PK(L2.z, L3.z);
    p3.x = PK(L0.w, L1.w); p3.y = PK(L2.w, L3.w);
    float4 w;
    w.x = p0.x; w.y = p0.y; w.z = p1.x; w.w = p1.y;
    *(float4*)&buf[s0] = w;                       // slot 4s4
    w.x = p1.x; w.y = p1.y; w.z = p2.x; w.w = p2.y;
    *(float4*)&buf[s0 + 4] = w;                   // slot 4s4+1
    w.x = p2.x; w.y = p2.y; w.z = p3.x; w.w = p3.y;
    *(float4*)&buf[s0 + 8] = w;                   // slot 4s4+2
    if (s4 < 3) *(float2*)&buf[s0 + 12] = p3;     // slot 4s4+3 lo
    if (s4 > 0) *(float2*)&buf[s0 - 2]  = p0;     // slot 4s4-1 hi
}

#define INTERP(ZB, BUF, G4, KK, IDX)                                           \
    {                                                                          \
        float o0[4], o1[4], o2[4], o3[4];                                      \
        _Pragma("unroll")                                                      \
        for (int v = 0; v < 4; ++v) {                                          \
            const float g = (v == 0) ? (G4).x : (v == 1) ? (G4).y              \
                          : (v == 2) ? (G4).z : (G4).w;                        \
            float t = fminf(fmaxf(g * 15.0f, 0.0f), 15.0f);                    \
            const int t0 = min((int)t, 14);                                    \
            const float ft = t - (float)t0;                                    \
            const __half2 ft2 = __float2half2_rn(ft);                          \
            const float zf = fminf((float)((KK) + v) * S_, 31.0f);             \
            const int z0g = (int)zf;                                           \
            const float fz = zf - (float)z0g;                                  \
            const int zi0 = z0g - (ZB);                                        \
            const int zi1 = min(z0g + 1, 31) - (ZB);                           \
            const __half2 fz2 = __float2half2_rn(fz);                          \
            const int CZ0 = zi0 * NODE_DW + (t0 << 2);                         \
            const int CZ1 = zi1 * NODE_DW + (t0 << 2);                         \
            const float4 a00 = *(const float4*)&(BUF)[AX0 + BY0 + CZ0];        \
            const float4 a01 = *(const float4*)&(BUF)[AX0 + BY1 + CZ0];        \
            const float4 a10 = *(const float4*)&(BUF)[AX1 + BY0 + CZ0];        \
            const float4 a11 = *(const float4*)&(BUF)[AX1 + BY1 + CZ0];        \
            const float4 b00 = *(const float4*)&(BUF)[AX0 + BY0 + CZ1];        \
            const float4 b01 = *(const float4*)&(BUF)[AX0 + BY1 + CZ1];        \
            const float4 b10 = *(const float4*)&(BUF)[AX1 + BY0 + CZ1];        \
            const float4 b11 = *(const float4*)&(BUF)[AX1 + BY1 + CZ1];        \
            __half2 Plo01 = __hmul2(W00, H2(a00.x));                           \
            __half2 Plo23 = __hmul2(W00, H2(a00.y));                           \
            __half2 Phi01 = __hmul2(W00, H2(a00.z));                           \
            __half2 Phi23 = __hmul2(W00, H2(a00.w));                           \
            Plo01 = __hfma2(W01, H2(a01.x), Plo01);                            \
            Plo23 = __hfma2(W01, H2(a01.y), Plo23);                            \
            Phi01 = __hfma2(W01, H2(a01.z), Phi01);                            \
            Phi23 = __hfma2(W01, H2(a01.w), Phi23);                            \
            Plo01 = __hfma2(W10, H2(a10.x), Plo01);                            \
            Plo23 = __hfma2(W10, H2(a10.y), Plo23);                            \
            Phi01 = __hfma2(W10, H2(a10.z), Phi01);                            \
            Phi23 = __hfma2(W10, H2(a10.w), Phi23);                            \
            Plo01 = __hfma2(W11, H2(a11.x), Plo01);                            \
            Plo23 = __hfma2(W11, H2(a11.y), Plo23);                            \
            Phi01 = __hfma2(W11, H2(a11.z), Phi01);                            \
            Phi23 = __hfma2(W11, H2(a11.w), Phi23);                            \
            __half2 Qlo01 = __hmul2(W00, H2(b00.x));                           \
            __half2 Qlo23 = __hmul2(W00, H2(b00.y));                           \
            __half2 Qhi01 = __hmul2(W00, H2(b00.z));                           \
            __half2 Qhi23 = __hmul2(W00, H2(b00.w));                           \
            Qlo01 = __hfma2(W01, H2(b01.x), Qlo01);                            \
            Qlo23 = __hfma2(W01, H2(b01.y), Qlo23);                            \
            Qhi01 = __hfma2(W01, H2(b01.z), Qhi01);                            \
            Qhi23 = __hfma2(W01, H2(b01.w), Qhi23);                            \
            Qlo01 = __hfma2(W10, H2(b10.x), Qlo01);                            \
            Qlo23 = __hfma2(W10, H2(b10.y), Qlo23);                            \
            Qhi01 = __hfma2(W10, H2(b10.z), Qhi01);                            \
            Qhi23 = __hfma2(W10, H2(b10.w), Qhi23);                            \
            Qlo01 = __hfma2(W11, H2(b11.x), Qlo01);                            \
            Qlo23 = __hfma2(W11, H2(b11.y), Qlo23);                            \
            Qhi01 = __hfma2(W11, H2(b11.z), Qhi01);                            \
            Qhi23 = __hfma2(W11, H2(b11.w), Qhi23);                            \
            const __half2 Rlo01 = __hfma2(fz2, __hsub2(Qlo01, Plo01), Plo01);  \
            const __half2 Rlo23 = __hfma2(fz2, __hsub2(Qlo23, Plo23), Plo23);  \
            const __half2 Rhi01 = __hfma2(fz2, __hsub2(Qhi01, Phi01), Phi01);  \
            const __half2 Rhi23 = __hfma2(fz2, __hsub2(Qhi23, Phi23), Phi23);  \
            const __half2 r01 = __hfma2(ft2, __hsub2(Rhi01, Rlo01), Rlo01);    \
            const __half2 r23 = __hfma2(ft2, __hsub2(Rhi23, Rlo23), Rlo23);    \
            o0[v] = __low2float(r01);                                          \
            o1[v] = __high2float(r01);                                         \
            o2[v] = __low2float(r23);                                          \
            o3[v] = __high2float(r23);                                         \
        }                                                                      \
        nt_store4(&out[(IDX)],             o0[0], o0[1], o0[2], o0[3]);        \
        nt_store4(&out[(IDX) + TOTAL],     o1[0], o1[1], o1[2], o1[3]);        \
        nt_store4(&out[(IDX) + 2 * TOTAL], o2[0], o2[1], o2[2], o2[3]);        \
        nt_store4(&out[(IDX) + 3 * TOTAL], o3[0], o3[1], o3[2], o3[3]);        \
    }

__global__ __launch_bounds__(256, 3) void bgrid_slice_v12(
    const float* __restrict__ bg,
    const float* __restrict__ gm,
    float* __restrict__ out)
{
    __shared__ __align__(16) float lds[2 * BUF_DW];   // 52224 B
    float* buf0 = lds;
    float* buf1 = lds + BUF_DW;

    const int tid = threadIdx.x;
    // XCD-chunked swizzle: 1024 blocks, 8 XCDs -> 128 contiguous pairs each.
    const int b = blockIdx.x;
    const int tile = ((b & 7) << 7) + (b >> 3);
    const int bm = tile & 3;               // k pair: k0 = 32*bm (+16)
    const int bj = (tile >> 2) & 15;
    const int bi = tile >> 6;

    const int i0 = bi * 8, j0 = bj * 8;
    const int k0A = bm * 32, k0B = k0A + 16;
    const int x_base = (int)((float)i0 * S_);
    const int y_base = (int)((float)j0 * S_);
    const int zbA = (int)((float)k0A * S_);
    const int zbB = (int)((float)k0B * S_);

    // ---- per-thread stage-item constants (q = tid, tid+256; 384 items) ----
    const int s4a = tid & 3;
    const int nodeA = tid >> 2;            // 0..63
    const bool act2 = (tid < 128);
    const int qB = tid + 256;
    const int s4b = qB & 3;
    const int nodeB = qB >> 2;             // 64..95

    int baseA, dstA, czA, baseB, dstB, czB;
    {
        const int a = nodeA / 24, rem = nodeA - a * 24;
        const int bb = rem / 6, cz = rem - bb * 6;
        const int gx = min(x_base + a, 31), gy = min(y_base + bb, 31);
        baseA = (((gx * 32 + gy) * 32) << 4) + (s4a << 2);
        dstA = nodeA * NODE_DW + (s4a << 4);
        czA = cz;
    }
    {
        const int a = nodeB / 24, rem = nodeB - a * 24;
        const int bb = rem / 6, cz = rem - bb * 6;
        const int gx = min(x_base + a, 31), gy = min(y_base + bb, 31);
        baseB = (((gx * 32 + gy) * 32) << 4) + (s4b << 2);
        dstB = nodeB * NODE_DW + (s4b << 4);
        czB = cz;
    }

    // ---- per-thread voxel ids; gm loads (nt) for both tiles ----
    const int kq = tid & 3;
    const int lj = (tid >> 2) & 7;
    const int li = tid >> 5;
    const int i = i0 + li, j = j0 + lj;
    const int kkA = k0A + (kq << 2), kkB = kkA + 16;
    const int idxA = (i << 14) | (j << 7) | kkA;
    const int idxB = idxA + 16;
    const vf4 g4av = __builtin_nontemporal_load((const vf4*)&gm[idxA]);
    const vf4 g4bv = __builtin_nontemporal_load((const vf4*)&gm[idxB]);
    float4 g4a; g4a.x = g4av.x; g4a.y = g4av.y; g4a.z = g4av.z; g4a.w = g4av.w;
    float4 g4b; g4b.x = g4bv.x; g4b.y = g4bv.y; g4b.z = g4bv.z; g4b.w = g4bv.w;

    // ---- prologue: stage tile0 into buf0 ----
    {
        const int gz = min(zbA + czA, 31);
        const int gb = baseA + (gz << 4);
        const float4 L0 = *(const float4*)&bg[gb];
        const float4 L1 = *(const float4*)&bg[gb + CH_STRIDE];
        const float4 L2 = *(const float4*)&bg[gb + 2 * CH_STRIDE];
        const float4 L3 = *(const float4*)&bg[gb + 3 * CH_STRIDE];
        pack_write(buf0, dstA, s4a, L0, L1, L2, L3);
    }
    if (act2) {
        const int gz = min(zbA + czB, 31);
        const int gb = baseB + (gz << 4);
        const float4 L0 = *(const float4*)&bg[gb];
        const float4 L1 = *(const float4*)&bg[gb + CH_STRIDE];
        const float4 L2 = *(const float4*)&bg[gb + 2 * CH_STRIDE];
        const float4 L3 = *(const float4*)&bg[gb + 3 * CH_STRIDE];
        pack_write(buf0, dstB, s4b, L0, L1, L2, L3);
    }
    __syncthreads();

    // ---- issue tile1 stage loads (kept in VGPRs across interp0) ----
    float4 MA0, MA1, MA2, MA3, MB0, MB1, MB2, MB3;
    {
        const int gz = min(zbB + czA, 31);
        const int gb = baseA + (gz << 4);
        MA0 = *(const float4*)&bg[gb];
        MA1 = *(const float4*)&bg[gb + CH_STRIDE];
        MA2 = *(const float4*)&bg[gb + 2 * CH_STRIDE];
        MA3 = *(const float4*)&bg[gb + 3 * CH_STRIDE];
    }
    if (act2) {
        const int gz = min(zbB + czB, 31);
        const int gb = baseB + (gz << 4);
        MB0 = *(const float4*)&bg[gb];
        MB1 = *(const float4*)&bg[gb + CH_STRIDE];
        MB2 = *(const float4*)&bg[gb + 2 * CH_STRIDE];
        MB3 = *(const float4*)&bg[gb + 3 * CH_STRIDE];
    }

    // ---- interp constants (shared by both tiles) ----
    const float xf = fminf((float)i * S_, 31.0f);
    const float yf = fminf((float)j * S_, 31.0f);
    const int x0g = (int)xf; const float fx = xf - (float)x0g;
    const int y0g = (int)yf; const float fy = yf - (float)y0g;
    const int AX0 = (x0g - x_base) * (NY * NZ * NODE_DW);
    const int AX1 = (min(x0g + 1, 31) - x_base) * (NY * NZ * NODE_DW);
    const int BY0 = (y0g - y_base) * (NZ * NODE_DW);
    const int BY1 = (min(y0g + 1, 31) - y_base) * (NZ * NODE_DW);

    const float wx1 = fx, wx0 = 1.0f - fx;
    const float wy1 = fy, wy0 = 1.0f - fy;
    const __half2 W00 = __float2half2_rn(wx0 * wy0);
    const __half2 W01 = __float2half2_rn(wx0 * wy1);
    const __half2 W10 = __float2half2_rn(wx1 * wy0);
    const __half2 W11 = __float2half2_rn(wx1 * wy1);

    // ---- interp tile0 (loads for tile1 in flight) ----
    INTERP(zbA, buf0, g4a, kkA, idxA);

    // keep pack after interp0 so the vmcnt wait lands here, not earlier
    __builtin_amdgcn_sched_barrier(0);

    // ---- pack + write tile1 ----
    pack_write(buf1, dstA, s4a, MA0, MA1, MA2, MA3);
    if (act2) pack_write(buf1, dstB, s4b, MB0, MB1, MB2, MB3);
    __syncthreads();

    // ---- interp tile1 ----
    INTERP(zbB, buf1, g4b, kkB, idxB);
}

extern "C" void kernel_launch(void* const* d_in, const int* in_sizes, int n_in,
                              void* d_out, int out_size, void* d_ws, size_t ws_size,
                              hipStream_t stream) {
    const float* bg = (const float*)d_in[0];
    const float* gm = (const float*)d_in[1];
    float* out = (float*)d_out;

    dim3 grid(1024);   // 16(bi) * 16(bj) * 4(bm pairs)
    dim3 block(256);
    bgrid_slice_v12<<<grid, block, 0, stream>>>(bg, gm, out);
}

// Round 14
// 19.248 us; speedup vs baseline: 1.0915x; 1.0915x over previous
//
#include <hip/hip_runtime.h>
#include <hip/hip_fp16.h>

// bg: (1,4,32,32,32,16) f32 ; gm: (1,1,128,128,128) f32 ; out: (1,4,128,128,128) f32
//
// v13 = v11b with 15-slot dup layout (node stride 60 dw = 240 B) and
// launch_bounds(256,6): LDS 23040 B -> 6 blocks/CU, 24 waves/CU.
// LDS per node: 15 slots of 16B; slot s = {t=s: pk(c0c1),pk(c2c3) |
// t=s+1: pk(c0c1),pk(c2c3)}, s in [0,14] (t0<=14 always).

#define S_ (31.0f / 127.0f)
#define CH_STRIDE 524288
#define TOTAL 2097152

#define NX 4
#define NY 4
#define NZ 6
#define NNODES (NX * NY * NZ)      // 96
#define NODE_DW 60                 // 15 slots * 4 dw = 240 B, 16B-aligned
#define LDS_DW (NNODES * NODE_DW)  // 5760 dw = 23040 B

#define PK(x, y) __builtin_bit_cast(float, __floats2half2_rn((x), (y)))
#define H2(f) __builtin_bit_cast(__half2, f)

typedef float vf4 __attribute__((ext_vector_type(4)));

__device__ __forceinline__ void nt_store4(float* p, float a, float b, float c, float d) {
    vf4 v; v.x = a; v.y = b; v.z = c; v.w = d;
    __builtin_nontemporal_store(v, (vf4*)p);
}

__global__ __launch_bounds__(256, 6) void bgrid_slice_v13(
    const float* __restrict__ bg,
    const float* __restrict__ gm,
    float* __restrict__ out)
{
    __shared__ __align__(16) float lds[LDS_DW];

    const int tid = threadIdx.x;
    // XCD-chunked swizzle: 2048 blocks, 8 XCDs -> 256 contiguous tiles each.
    const int b = blockIdx.x;
    const int tile = ((b & 7) << 8) + (b >> 3);
    const int bk = tile & 7;
    const int bj = (tile >> 3) & 15;
    const int bi = tile >> 7;

    const int i0 = bi * 8, j0 = bj * 8, k0 = bk * 16;
    const int x_base = (int)((float)i0 * S_);
    const int y_base = (int)((float)j0 * S_);
    const int z_base = (int)((float)k0 * S_);

    // ---- per-thread voxel ids; issue gm load before staging ----
    const int kq = tid & 3;
    const int lj = (tid >> 2) & 7;
    const int li = tid >> 5;
    const int i = i0 + li, j = j0 + lj;
    const int kk = k0 + (kq << 2);
    const int idx = (i << 14) | (j << 7) | kk;
    const float4 g4 = *(const float4*)&gm[idx];

    // ---- stage: 96 nodes * 4 segments = 384 items ----
    #pragma unroll
    for (int it = 0; it < 2; ++it) {
        const int q = tid + (it << 8);
        if (q < 384) {
            const int s4 = q & 3;            // t segment: t = 4*s4 .. 4*s4+3
            const int node = q >> 2;         // 0..95
            const int a = node / 24;
            const int rem = node - a * 24;
            const int bb = rem / 6;
            const int cz = rem - bb * 6;
            const int gx = min(x_base + a, 31);
            const int gy = min(y_base + bb, 31);
            const int gz = min(z_base + cz, 31);
            const int gbase = (((gx * 32 + gy) * 32 + gz) << 4) + (s4 << 2);

            const float4 L0 = *(const float4*)&bg[gbase];
            const float4 L1 = *(const float4*)&bg[gbase + CH_STRIDE];
            const float4 L2 = *(const float4*)&bg[gbase + 2 * CH_STRIDE];
            const float4 L3 = *(const float4*)&bg[gbase + 3 * CH_STRIDE];

            float2 p0, p1, p2, p3;           // lo2(t) for t = 4*s4+0..3
            p0.x = PK(L0.x, L1.x); p0.y = PK(L2.x, L3.x);
            p1.x = PK(L0.y, L1.y); p1.y = PK(L2.y, L3.y);
            p2.x = PK(L0.z, L1.z); p2.y = PK(L2.z, L3.z);
            p3.x = PK(L0.w, L1.w); p3.y = PK(L2.w, L3.w);

            const int s0 = node * NODE_DW + (s4 << 4);   // dw of slot 4*s4
            float4 w;
            w.x = p0.x; w.y = p0.y; w.z = p1.x; w.w = p1.y;
            *(float4*)&lds[s0] = w;                       // slot 4s4
            w.x = p1.x; w.y = p1.y; w.z = p2.x; w.w = p2.y;
            *(float4*)&lds[s0 + 4] = w;                   // slot 4s4+1
            w.x = p2.x; w.y = p2.y; w.z = p3.x; w.w = p3.y;
            *(float4*)&lds[s0 + 8] = w;                   // slot 4s4+2
            if (s4 < 3) *(float2*)&lds[s0 + 12] = p3;     // slot 4s4+3 lo
            if (s4 > 0) *(float2*)&lds[s0 - 2]  = p0;     // slot 4s4-1 hi
        }
    }
    __syncthreads();

    // ---- interp (verbatim v11b body, stride 60) ----
    const float xf = fminf((float)i * S_, 31.0f);
    const float yf = fminf((float)j * S_, 31.0f);
    const int x0g = (int)xf; const float fx = xf - (float)x0g;
    const int y0g = (int)yf; const float fy = yf - (float)y0g;
    const int xi0 = x0g - x_base, xi1 = min(x0g + 1, 31) - x_base;
    const int yi0 = y0g - y_base, yi1 = min(y0g + 1, 31) - y_base;

    const int AX0 = xi0 * (NY * NZ * NODE_DW);
    const int AX1 = xi1 * (NY * NZ * NODE_DW);
    const int BY0 = yi0 * (NZ * NODE_DW);
    const int BY1 = yi1 * (NZ * NODE_DW);

    const float wx1 = fx, wx0 = 1.0f - fx;
    const float wy1 = fy, wy0 = 1.0f - fy;
    const __half2 W00 = __float2half2_rn(wx0 * wy0);
    const __half2 W01 = __float2half2_rn(wx0 * wy1);
    const __half2 W10 = __float2half2_rn(wx1 * wy0);
    const __half2 W11 = __float2half2_rn(wx1 * wy1);

    float o0[4], o1[4], o2[4], o3[4];

#pragma unroll
    for (int v = 0; v < 4; ++v) {
        const float g = (v == 0) ? g4.x : (v == 1) ? g4.y : (v == 2) ? g4.z : g4.w;
        float t = fminf(fmaxf(g * 15.0f, 0.0f), 15.0f);
        const int t0 = min((int)t, 14);
        const float ft = t - (float)t0;
        const __half2 ft2 = __float2half2_rn(ft);

        const float zf = fminf((float)(kk + v) * S_, 31.0f);
        const int z0g = (int)zf;
        const float fz = zf - (float)z0g;
        const int zi0 = z0g - z_base;
        const int zi1 = min(z0g + 1, 31) - z_base;
        const __half2 fz2 = __float2half2_rn(fz);

        const int CZ0 = zi0 * NODE_DW + (t0 << 2);
        const int CZ1 = zi1 * NODE_DW + (t0 << 2);

        const float4 a00 = *(const float4*)&lds[AX0 + BY0 + CZ0];
        const float4 a01 = *(const float4*)&lds[AX0 + BY1 + CZ0];
        const float4 a10 = *(const float4*)&lds[AX1 + BY0 + CZ0];
        const float4 a11 = *(const float4*)&lds[AX1 + BY1 + CZ0];
        const float4 b00 = *(const float4*)&lds[AX0 + BY0 + CZ1];
        const float4 b01 = *(const float4*)&lds[AX0 + BY1 + CZ1];
        const float4 b10 = *(const float4*)&lds[AX1 + BY0 + CZ1];
        const float4 b11 = *(const float4*)&lds[AX1 + BY1 + CZ1];

        __half2 Plo01 = __hmul2(W00, H2(a00.x));
        __half2 Plo23 = __hmul2(W00, H2(a00.y));
        __half2 Phi01 = __hmul2(W00, H2(a00.z));
        __half2 Phi23 = __hmul2(W00, H2(a00.w));
        Plo01 = __hfma2(W01, H2(a01.x), Plo01);
        Plo23 = __hfma2(W01, H2(a01.y), Plo23);
        Phi01 = __hfma2(W01, H2(a01.z), Phi01);
        Phi23 = __hfma2(W01, H2(a01.w), Phi23);
        Plo01 = __hfma2(W10, H2(a10.x), Plo01);
        Plo23 = __hfma2(W10, H2(a10.y), Plo23);
        Phi01 = __hfma2(W10, H2(a10.z), Phi01);
        Phi23 = __hfma2(W10, H2(a10.w), Phi23);
        Plo01 = __hfma2(W11, H2(a11.x), Plo01);
        Plo23 = __hfma2(W11, H2(a11.y), Plo23);
        Phi01 = __hfma2(W11, H2(a11.z), Phi01);
        Phi23 = __hfma2(W11, H2(a11.w), Phi23);

        __half2 Qlo01 = __hmul2(W00, H2(b00.x));
        __half2 Qlo23 = __hmul2(W00, H2(b00.y));
        __half2 Qhi01 = __hmul2(W00, H2(b00.z));
        __half2 Qhi23 = __hmul2(W00, H2(b00.w));
        Qlo01 = __hfma2(W01, H2(b01.x), Qlo01);
        Qlo23 = __hfma2(W01, H2(b01.y), Qlo23);
        Qhi01 = __hfma2(W01, H2(b01.z), Qhi01);
        Qhi23 = __hfma2(W01, H2(b01.w), Qhi23);
        Qlo01 = __hfma2(W10, H2(b10.x), Qlo01);
        Qlo23 = __hfma2(W10, H2(b10.y), Qlo23);
        Qhi01 = __hfma2(W10, H2(b10.z), Qhi01);
        Qhi23 = __hfma2(W10, H2(b10.w), Qhi23);
        Qlo01 = __hfma2(W11, H2(b11.x), Qlo01);
        Qlo23 = __hfma2(W11, H2(b11.y), Qlo23);
        Qhi01 = __hfma2(W11, H2(b11.z), Qhi01);
        Qhi23 = __hfma2(W11, H2(b11.w), Qhi23);

        const __half2 Rlo01 = __hfma2(fz2, __hsub2(Qlo01, Plo01), Plo01);
        const __half2 Rlo23 = __hfma2(fz2, __hsub2(Qlo23, Plo23), Plo23);
        const __half2 Rhi01 = __hfma2(fz2, __hsub2(Qhi01, Phi01), Phi01);
        const __half2 Rhi23 = __hfma2(fz2, __hsub2(Qhi23, Phi23), Phi23);

        const __half2 r01 = __hfma2(ft2, __hsub2(Rhi01, Rlo01), Rlo01);
        const __half2 r23 = __hfma2(ft2, __hsub2(Rhi23, Rlo23), Rlo23);

        o0[v] = __low2float(r01);
        o1[v] = __high2float(r01);
        o2[v] = __low2float(r23);
        o3[v] = __high2float(r23);
    }

    nt_store4(&out[idx],             o0[0], o0[1], o0[2], o0[3]);
    nt_store4(&out[idx + TOTAL],     o1[0], o1[1], o1[2], o1[3]);
    nt_store4(&out[idx + 2 * TOTAL], o2[0], o2[1], o2[2], o2[3]);
    nt_store4(&out[idx + 3 * TOTAL], o3[0], o3[1], o3[2], o3[3]);
}

extern "C" void kernel_launch(void* const* d_in, const int* in_sizes, int n_in,
                              void* d_out, int out_size, void* d_ws, size_t ws_size,
                              hipStream_t stream) {
    const float* bg = (const float*)d_in[0];
    const float* gm = (const float*)d_in[1];
    float* out = (float*)d_out;

    dim3 grid(2048);   // (128/8)*(128/8)*(128/16)
    dim3 block(256);
    bgrid_slice_v13<<<grid, block, 0, stream>>>(bg, gm, out);
}

// Round 15
// 16.750 us; speedup vs baseline: 1.2543x; 1.1492x over previous
//
#include <hip/hip_runtime.h>
#include <hip/hip_fp16.h>

// bg: (1,4,32,32,32,16) f32 ; gm: (1,1,128,128,128) f32 ; out: (1,4,128,128,128) f32
//
// v14 = v11b structure with 8x8x32 tile (512 thr, 4 vox/thread).
// Staged nodes 4x * 4y * 10z = 160, dup-slot fp16 layout, NODE_DW 68.
// LDS 43520 B -> 3 blocks/CU (24 waves/CU). XCD swizzle, nt gm loads,
// nt out stores. Interp body verbatim v11b.

#define S_ (31.0f / 127.0f)
#define CH_STRIDE 524288
#define TOTAL 2097152

#define NX 4
#define NY 4
#define NZ 10
#define NNODES (NX * NY * NZ)      // 160
#define NODE_DW 68
#define LDS_DW (NNODES * NODE_DW)  // 10880 dw = 43520 B

#define PK(x, y) __builtin_bit_cast(float, __floats2half2_rn((x), (y)))
#define H2(f) __builtin_bit_cast(__half2, f)

typedef float vf4 __attribute__((ext_vector_type(4)));

__device__ __forceinline__ void nt_store4(float* p, float a, float b, float c, float d) {
    vf4 v; v.x = a; v.y = b; v.z = c; v.w = d;
    __builtin_nontemporal_store(v, (vf4*)p);
}

__global__ __launch_bounds__(512, 6) void bgrid_slice_v14(
    const float* __restrict__ bg,
    const float* __restrict__ gm,
    float* __restrict__ out)
{
    __shared__ __align__(16) float lds[LDS_DW];

    const int tid = threadIdx.x;
    // XCD-chunked swizzle: 1024 blocks, 8 XCDs -> 128 contiguous tiles each.
    const int b = blockIdx.x;
    const int tile = ((b & 7) << 7) + (b >> 3);
    const int bk = tile & 3;
    const int bj = (tile >> 2) & 15;
    const int bi = tile >> 6;

    const int i0 = bi * 8, j0 = bj * 8, k0 = bk * 32;
    const int x_base = (int)((float)i0 * S_);
    const int y_base = (int)((float)j0 * S_);
    const int z_base = (int)((float)k0 * S_);

    // ---- per-thread voxel ids; issue gm load (nt) before staging ----
    const int kq = tid & 7;
    const int lj = (tid >> 3) & 7;
    const int li = tid >> 6;
    const int i = i0 + li, j = j0 + lj;
    const int kk = k0 + (kq << 2);
    const int idx = (i << 14) | (j << 7) | kk;
    const vf4 g4v = __builtin_nontemporal_load((const vf4*)&gm[idx]);
    float4 g4; g4.x = g4v.x; g4.y = g4v.y; g4.z = g4v.z; g4.w = g4v.w;

    // ---- stage: 160 nodes * 4 segments = 640 items ----
    #pragma unroll
    for (int it = 0; it < 2; ++it) {
        const int q = tid + (it << 9);
        if (q < 640) {
            const int s4 = q & 3;            // t segment: t = 4*s4 .. 4*s4+3
            const int node = q >> 2;         // 0..159
            const int a = node / 40;
            const int rem = node - a * 40;
            const int bb = rem / 10;
            const int cz = rem - bb * 10;
            const int gx = min(x_base + a, 31);
            const int gy = min(y_base + bb, 31);
            const int gz = min(z_base + cz, 31);
            const int gbase = (((gx * 32 + gy) * 32 + gz) << 4) + (s4 << 2);

            const float4 L0 = *(const float4*)&bg[gbase];
            const float4 L1 = *(const float4*)&bg[gbase + CH_STRIDE];
            const float4 L2 = *(const float4*)&bg[gbase + 2 * CH_STRIDE];
            const float4 L3 = *(const float4*)&bg[gbase + 3 * CH_STRIDE];

            float2 p0, p1, p2, p3;           // lo2(t) for t = 4*s4+0..3
            p0.x = PK(L0.x, L1.x); p0.y = PK(L2.x, L3.x);
            p1.x = PK(L0.y, L1.y); p1.y = PK(L2.y, L3.y);
            p2.x = PK(L0.z, L1.z); p2.y = PK(L2.z, L3.z);
            p3.x = PK(L0.w, L1.w); p3.y = PK(L2.w, L3.w);

            const int s0 = node * NODE_DW + (s4 << 4);   // dw of slot 4*s4
            float4 w;
            w.x = p0.x; w.y = p0.y; w.z = p1.x; w.w = p1.y;
            *(float4*)&lds[s0] = w;                       // slot 4s4
            w.x = p1.x; w.y = p1.y; w.z = p2.x; w.w = p2.y;
            *(float4*)&lds[s0 + 4] = w;                   // slot 4s4+1
            w.x = p2.x; w.y = p2.y; w.z = p3.x; w.w = p3.y;
            *(float4*)&lds[s0 + 8] = w;                   // slot 4s4+2
            if (s4 < 3) *(float2*)&lds[s0 + 12] = p3;     // slot 4s4+3 lo
            if (s4 > 0) *(float2*)&lds[s0 - 2]  = p0;     // slot 4s4-1 hi
        }
    }
    __syncthreads();

    // ---- interp (verbatim v11b body, NZ=10 strides) ----
    const float xf = fminf((float)i * S_, 31.0f);
    const float yf = fminf((float)j * S_, 31.0f);
    const int x0g = (int)xf; const float fx = xf - (float)x0g;
    const int y0g = (int)yf; const float fy = yf - (float)y0g;
    const int xi0 = x0g - x_base, xi1 = min(x0g + 1, 31) - x_base;
    const int yi0 = y0g - y_base, yi1 = min(y0g + 1, 31) - y_base;

    const int AX0 = xi0 * (NY * NZ * NODE_DW);
    const int AX1 = xi1 * (NY * NZ * NODE_DW);
    const int BY0 = yi0 * (NZ * NODE_DW);
    const int BY1 = yi1 * (NZ * NODE_DW);

    const float wx1 = fx, wx0 = 1.0f - fx;
    const float wy1 = fy, wy0 = 1.0f - fy;
    const __half2 W00 = __float2half2_rn(wx0 * wy0);
    const __half2 W01 = __float2half2_rn(wx0 * wy1);
    const __half2 W10 = __float2half2_rn(wx1 * wy0);
    const __half2 W11 = __float2half2_rn(wx1 * wy1);

    float o0[4], o1[4], o2[4], o3[4];

#pragma unroll
    for (int v = 0; v < 4; ++v) {
        const float g = (v == 0) ? g4.x : (v == 1) ? g4.y : (v == 2) ? g4.z : g4.w;
        float t = fminf(fmaxf(g * 15.0f, 0.0f), 15.0f);
        const int t0 = min((int)t, 14);
        const float ft = t - (float)t0;
        const __half2 ft2 = __float2half2_rn(ft);

        const float zf = fminf((float)(kk + v) * S_, 31.0f);
        const int z0g = (int)zf;
        const float fz = zf - (float)z0g;
        const int zi0 = z0g - z_base;
        const int zi1 = min(z0g + 1, 31) - z_base;
        const __half2 fz2 = __float2half2_rn(fz);

        const int CZ0 = zi0 * NODE_DW + (t0 << 2);
        const int CZ1 = zi1 * NODE_DW + (t0 << 2);

        const float4 a00 = *(const float4*)&lds[AX0 + BY0 + CZ0];
        const float4 a01 = *(const float4*)&lds[AX0 + BY1 + CZ0];
        const float4 a10 = *(const float4*)&lds[AX1 + BY0 + CZ0];
        const float4 a11 = *(const float4*)&lds[AX1 + BY1 + CZ0];
        const float4 b00 = *(const float4*)&lds[AX0 + BY0 + CZ1];
        const float4 b01 = *(const float4*)&lds[AX0 + BY1 + CZ1];
        const float4 b10 = *(const float4*)&lds[AX1 + BY0 + CZ1];
        const float4 b11 = *(const float4*)&lds[AX1 + BY1 + CZ1];

        __half2 Plo01 = __hmul2(W00, H2(a00.x));
        __half2 Plo23 = __hmul2(W00, H2(a00.y));
        __half2 Phi01 = __hmul2(W00, H2(a00.z));
        __half2 Phi23 = __hmul2(W00, H2(a00.w));
        Plo01 = __hfma2(W01, H2(a01.x), Plo01);
        Plo23 = __hfma2(W01, H2(a01.y), Plo23);
        Phi01 = __hfma2(W01, H2(a01.z), Phi01);
        Phi23 = __hfma2(W01, H2(a01.w), Phi23);
        Plo01 = __hfma2(W10, H2(a10.x), Plo01);
        Plo23 = __hfma2(W10, H2(a10.y), Plo23);
        Phi01 = __hfma2(W10, H2(a10.z), Phi01);
        Phi23 = __hfma2(W10, H2(a10.w), Phi23);
        Plo01 = __hfma2(W11, H2(a11.x), Plo01);
        Plo23 = __hfma2(W11, H2(a11.y), Plo23);
        Phi01 = __hfma2(W11, H2(a11.z), Phi01);
        Phi23 = __hfma2(W11, H2(a11.w), Phi23);

        __half2 Qlo01 = __hmul2(W00, H2(b00.x));
        __half2 Qlo23 = __hmul2(W00, H2(b00.y));
        __half2 Qhi01 = __hmul2(W00, H2(b00.z));
        __half2 Qhi23 = __hmul2(W00, H2(b00.w));
        Qlo01 = __hfma2(W01, H2(b01.x), Qlo01);
        Qlo23 = __hfma2(W01, H2(b01.y), Qlo23);
        Qhi01 = __hfma2(W01, H2(b01.z), Qhi01);
        Qhi23 = __hfma2(W01, H2(b01.w), Qhi23);
        Qlo01 = __hfma2(W10, H2(b10.x), Qlo01);
        Qlo23 = __hfma2(W10, H2(b10.y), Qlo23);
        Qhi01 = __hfma2(W10, H2(b10.z), Qhi01);
        Qhi23 = __hfma2(W10, H2(b10.w), Qhi23);
        Qlo01 = __hfma2(W11, H2(b11.x), Qlo01);
        Qlo23 = __hfma2(W11, H2(b11.y), Qlo23);
        Qhi01 = __hfma2(W11, H2(b11.z), Qhi01);
        Qhi23 = __hfma2(W11, H2(b11.w), Qhi23);

        const __half2 Rlo01 = __hfma2(fz2, __hsub2(Qlo01, Plo01), Plo01);
        const __half2 Rlo23 = __hfma2(fz2, __hsub2(Qlo23, Plo23), Plo23);
        const __half2 Rhi01 = __hfma2(fz2, __hsub2(Qhi01, Phi01), Phi01);
        const __half2 Rhi23 = __hfma2(fz2, __hsub2(Qhi23, Phi23), Phi23);

        const __half2 r01 = __hfma2(ft2, __hsub2(Rhi01, Rlo01), Rlo01);
        const __half2 r23 = __hfma2(ft2, __hsub2(Rhi23, Rlo23), Rlo23);

        o0[v] = __low2float(r01);
        o1[v] = __high2float(r01);
        o2[v] = __low2float(r23);
        o3[v] = __high2float(r23);
    }

    nt_store4(&out[idx],             o0[0], o0[1], o0[2], o0[3]);
    nt_store4(&out[idx + TOTAL],     o1[0], o1[1], o1[2], o1[3]);
    nt_store4(&out[idx + 2 * TOTAL], o2[0], o2[1], o2[2], o2[3]);
    nt_store4(&out[idx + 3 * TOTAL], o3[0], o3[1], o3[2], o3[3]);
}

extern "C" void kernel_launch(void* const* d_in, const int* in_sizes, int n_in,
                              void* d_out, int out_size, void* d_ws, size_t ws_size,
                              hipStream_t stream) {
    const float* bg = (const float*)d_in[0];
    const float* gm = (const float*)d_in[1];
    float* out = (float*)d_out;

    dim3 grid(1024);   // (128/8)*(128/8)*(128/32)
    dim3 block(512);
    bgrid_slice_v14<<<grid, block, 0, stream>>>(bg, gm, out);
}